// Round 13
// baseline (1844.320 us; speedup 1.0000x reference)
//
#include <hip/hip_runtime.h>
#include <cstdint>
#include <cstring>

#define H_DIM 512
#define B_DIM 256
#define T_DIM 256

typedef __bf16 bf16x8 __attribute__((ext_vector_type(8)));
typedef __bf16 bf16x4 __attribute__((ext_vector_type(4)));
typedef float  f32x4  __attribute__((ext_vector_type(4)));
typedef unsigned long long ull;

__device__ __forceinline__ void cvt_split(float4 a, float4 b, bf16x8& h, bf16x8& lo) {
  const float v[8] = {a.x, a.y, a.z, a.w, b.x, b.y, b.z, b.w};
#pragma unroll
  for (int j = 0; j < 8; ++j) {
    h[j]  = (__bf16)v[j];
    lo[j] = (__bf16)(v[j] - (float)h[j]);
  }
}

__device__ __forceinline__ unsigned pack2bf(float a, float b) {
  const __bf16 ba = (__bf16)a, bb = (__bf16)b;
  unsigned short sa, sb;
  __builtin_memcpy(&sa, &ba, 2);
  __builtin_memcpy(&sb, &bb, 2);
  return (unsigned)sa | ((unsigned)sb << 16);
}

// =====================================================================
// K1: Ux[(t*256+b)*512 + i] = sum_k x[b][t][k]*U[i][k] + bias[i]
// bf16 split-MFMA (xh@Uh + xh@Ul + xl@Uh ~ f32 accurate), f32 output.
// (R7-proven)
// =====================================================================
__global__ __launch_bounds__(256, 2) void k1_ux(const float* __restrict__ x,
                                                const float* __restrict__ U,
                                                const float* __restrict__ bias,
                                                float* __restrict__ Ux) {
  __shared__ __align__(16) __bf16 XH[128][40];
  __shared__ __align__(16) __bf16 XL[128][40];
  __shared__ __align__(16) __bf16 UH[128][40];
  __shared__ __align__(16) __bf16 UL[128][40];

  const int tid = threadIdx.x;
  const int l   = tid & 63;
  const int w   = tid >> 6;
  const int wm  = w >> 1;
  const int wn  = w & 1;
  const int r0  = blockIdx.x * 128;
  const int i0  = blockIdx.y * 128;
  const int t   = r0 >> 8;
  const int b0  = r0 & 255;

  const int srow  = tid >> 1;
  const int shalf = tid & 1;

  f32x4 acc[4][4];
#pragma unroll
  for (int mi = 0; mi < 4; ++mi)
#pragma unroll
    for (int ni = 0; ni < 4; ++ni) acc[mi][ni] = (f32x4){0.f, 0.f, 0.f, 0.f};

  const int lrow = l & 15;
  const int lgrn = (l >> 4) * 8;

  for (int k0 = 0; k0 < H_DIM; k0 += 32) {
    __syncthreads();
    {
      const float* xsrc = x + ((size_t)(b0 + srow) * T_DIM + t) * H_DIM + k0 + shalf * 16;
      const float* usrc = U + (size_t)(i0 + srow) * H_DIM + k0 + shalf * 16;
      bf16x8 h0, l0, h1, l1;
      cvt_split(*(const float4*)xsrc, *(const float4*)(xsrc + 4), h0, l0);
      cvt_split(*(const float4*)(xsrc + 8), *(const float4*)(xsrc + 12), h1, l1);
      *(bf16x8*)&XH[srow][shalf * 16]     = h0;
      *(bf16x8*)&XH[srow][shalf * 16 + 8] = h1;
      *(bf16x8*)&XL[srow][shalf * 16]     = l0;
      *(bf16x8*)&XL[srow][shalf * 16 + 8] = l1;
      cvt_split(*(const float4*)usrc, *(const float4*)(usrc + 4), h0, l0);
      cvt_split(*(const float4*)(usrc + 8), *(const float4*)(usrc + 12), h1, l1);
      *(bf16x8*)&UH[srow][shalf * 16]     = h0;
      *(bf16x8*)&UH[srow][shalf * 16 + 8] = h1;
      *(bf16x8*)&UL[srow][shalf * 16]     = l0;
      *(bf16x8*)&UL[srow][shalf * 16 + 8] = l1;
    }
    __syncthreads();

    bf16x8 ah[4], al[4], bh[4], blo[4];
#pragma unroll
    for (int mi = 0; mi < 4; ++mi) {
      ah[mi] = *(const bf16x8*)&XH[wm * 64 + mi * 16 + lrow][lgrn];
      al[mi] = *(const bf16x8*)&XL[wm * 64 + mi * 16 + lrow][lgrn];
    }
#pragma unroll
    for (int ni = 0; ni < 4; ++ni) {
      bh[ni]  = *(const bf16x8*)&UH[wn * 64 + ni * 16 + lrow][lgrn];
      blo[ni] = *(const bf16x8*)&UL[wn * 64 + ni * 16 + lrow][lgrn];
    }
#pragma unroll
    for (int mi = 0; mi < 4; ++mi)
#pragma unroll
      for (int ni = 0; ni < 4; ++ni) {
        acc[mi][ni] = __builtin_amdgcn_mfma_f32_16x16x32_bf16(ah[mi], bh[ni],  acc[mi][ni], 0, 0, 0);
        acc[mi][ni] = __builtin_amdgcn_mfma_f32_16x16x32_bf16(ah[mi], blo[ni], acc[mi][ni], 0, 0, 0);
        acc[mi][ni] = __builtin_amdgcn_mfma_f32_16x16x32_bf16(al[mi], bh[ni],  acc[mi][ni], 0, 0, 0);
      }
  }

  float bvv[4];
#pragma unroll
  for (int ni = 0; ni < 4; ++ni) bvv[ni] = bias[i0 + wn * 64 + ni * 16 + lrow];
#pragma unroll
  for (int mi = 0; mi < 4; ++mi)
#pragma unroll
    for (int ni = 0; ni < 4; ++ni) {
      const int col = i0 + wn * 64 + ni * 16 + lrow;
      const int row = r0 + wm * 64 + mi * 16 + (l >> 4) * 4;
#pragma unroll
      for (int r = 0; r < 4; ++r)
        Ux[(size_t)(row + r) * H_DIM + col] = acc[mi][ni][r] + bvv[ni];
    }
}

// =====================================================================
// K2: scan (R12 structure + INCREMENTAL-RETRY packet polling).
//   64 blocks x 512 threads. bid = slice*8 + g.
//   Exchange: pkt[buf][g][row<32][fp<256] : u64 = [seq:32 | 2 x bf16].
//   Producer: 2 x 8B relaxed-atomic stores (fp = slice*32 + (tid&15)*2).
//   Consumer: per-thread 16-bit valid mask; each sweep reloads ONLY
//   still-invalid packets (lanes with full mask issue zero loads) ->
//   poll traffic ~8-16x lower than R12's full resweep; detect == arrival.
//   WAR/replay safety unchanged from R12 (seq validation + pkt memset).
// =====================================================================
__device__ __forceinline__ unsigned swz(unsigned row, unsigned b) {
  return row * 1024u + (b ^ ((row & 7u) << 4));
}

__global__ __launch_bounds__(512, 1) void k2_scan(const float* __restrict__ W,
                                                  const float* __restrict__ Amat,
                                                  const float* __restrict__ y0,
                                                  const float* __restrict__ Ux,
                                                  const float* __restrict__ Wro,
                                                  ull* __restrict__ pkt,          // 2 x 65536 u64
                                                  float* __restrict__ plog) {     // [T][8][B]
  __shared__ __align__(16) char Ylds[32 * 1024];   // 32 rows x 512 bf16, swizzled
  __shared__ float Xex[2][2][32][68];              // [otype][khalf][b][f] padded
  const int tid   = threadIdx.x;
  const int g     = blockIdx.x & 7;
  const int slice = blockIdx.x >> 3;
  const int fbase = slice * 64;

  const int l     = tid & 63;
  const int w     = tid >> 6;        // 0..7
  const int otype = w >> 2;          // 0 = pre (W), 1 = gate (A)
  const int ng    = (w >> 1) & 1;    // feature 32-group within 64
  const int khalf = w & 1;           // K 256-split

  const int bl     = tid >> 4;       // batch 0..31
  const int f0i    = (tid & 15) * 4; // feature 0..60 (within 64-slice)
  const int b_glob = g * 32 + bl;

  // ---- own y0 state -> registers ----
  float4 yst = *(const float4*)(y0 + (size_t)b_glob * H_DIM + fbase + f0i);
  const float4 wrov = *(const float4*)(Wro + fbase + f0i);

  // ---- W/A fragments -> VGPRs (once) ----
  const int n0    = l & 15;
  const int kfrag = khalf * 256 + ((l >> 4) * 8);
  const float* Bsrc = otype ? Amat : W;
  bf16x8 bfr[2][8];
#pragma unroll
  for (int ks = 0; ks < 8; ++ks) {
#pragma unroll
    for (int h2 = 0; h2 < 2; ++h2) {
      const float* src = Bsrc + (size_t)(fbase + ng * 32 + n0 + h2 * 16) * H_DIM + kfrag + ks * 32;
      const float4 s0 = *(const float4*)src;
      const float4 s1 = *(const float4*)(src + 4);
      bf16x8 v;
      v[0] = (__bf16)s0.x; v[1] = (__bf16)s0.y; v[2] = (__bf16)s0.z; v[3] = (__bf16)s0.w;
      v[4] = (__bf16)s1.x; v[5] = (__bf16)s1.y; v[6] = (__bf16)s1.z; v[7] = (__bf16)s1.w;
      bfr[h2][ks] = v;
    }
  }

  const unsigned ra0  = (unsigned)(l & 15);
  const unsigned ra1  = ra0 + 16u;
  const unsigned coff = (unsigned)((l >> 4) * 16 + khalf * 512);

  // staging constants: this thread stages row = tid>>4, fp = (tid&15)+16j
  const unsigned srow = (unsigned)(tid >> 4);
  const unsigned scol = (unsigned)(tid & 15);
  // producer constants: global fp = (fbase + f0i)/2 = slice*32 + (tid&15)*2
  const size_t prod_base = (size_t)g * 8192 + (size_t)bl * 256
                         + (size_t)slice * 32 + (size_t)(tid & 15) * 2;

  for (int t = 0; t < T_DIM; ++t) {
    // input-path term: issue before the packet wait (latency hides under it)
    const float4 uxv = *(const float4*)(Ux + ((size_t)t * B_DIM + b_glob) * H_DIM + fbase + f0i);

    // ---- stage y_t -> Ylds ----
    if (t == 0) {
#pragma unroll
      for (int j = 0; j < 16; ++j) {
        const unsigned fp = scol + 16u * j;
        const float2 v = *(const float2*)(y0 + (size_t)(g * 32 + srow) * H_DIM + fp * 2);
        *(unsigned*)(Ylds + srow * 1024u + ((fp * 4u) ^ ((srow & 7u) << 4))) = pack2bf(v.x, v.y);
      }
    } else {
      // incremental-retry fused poll+load: reload ONLY invalid packets
      const ull* src = pkt + (size_t)(t & 1) * 65536 + (size_t)g * 8192
                     + (size_t)srow * 256 + scol;
      ull pk[16];
      unsigned okm = 0;
      for (;;) {
#pragma unroll
        for (int j = 0; j < 16; ++j) {
          if (!(okm & (1u << j))) {
            pk[j] = __hip_atomic_load(src + (size_t)j * 16,
                                      __ATOMIC_RELAXED, __HIP_MEMORY_SCOPE_AGENT);
            if ((unsigned)(pk[j] >> 32) == (unsigned)t) okm |= (1u << j);
          }
        }
        if (__all(okm == 0xFFFFu)) break;
        __builtin_amdgcn_s_sleep(1);
      }
#pragma unroll
      for (int j = 0; j < 16; ++j) {
        const unsigned fp = scol + 16u * j;
        *(unsigned*)(Ylds + srow * 1024u + ((fp * 4u) ^ ((srow & 7u) << 4))) = (unsigned)pk[j];
      }
    }
    __syncthreads();

    // ---- MFMA: 2M x 2N x 8K per wave ----
    f32x4 acc00 = {0.f, 0.f, 0.f, 0.f};
    f32x4 acc01 = {0.f, 0.f, 0.f, 0.f};
    f32x4 acc10 = {0.f, 0.f, 0.f, 0.f};
    f32x4 acc11 = {0.f, 0.f, 0.f, 0.f};
#pragma unroll
    for (int ks = 0; ks < 8; ++ks) {
      const unsigned kb = coff + (unsigned)ks * 64u;
      const bf16x8 a0 = *(const bf16x8*)(Ylds + swz(ra0, kb));
      const bf16x8 a1 = *(const bf16x8*)(Ylds + swz(ra1, kb));
      acc00 = __builtin_amdgcn_mfma_f32_16x16x32_bf16(a0, bfr[0][ks], acc00, 0, 0, 0);
      acc01 = __builtin_amdgcn_mfma_f32_16x16x32_bf16(a0, bfr[1][ks], acc01, 0, 0, 0);
      acc10 = __builtin_amdgcn_mfma_f32_16x16x32_bf16(a1, bfr[0][ks], acc10, 0, 0, 0);
      acc11 = __builtin_amdgcn_mfma_f32_16x16x32_bf16(a1, bfr[1][ks], acc11, 0, 0, 0);
    }

    // ---- partial-tile exchange ----
    {
      const int lr = (l >> 4) * 4;
      const int lc = l & 15;
#pragma unroll
      for (int r = 0; r < 4; ++r) {
        Xex[otype][khalf][lr + r][ng * 32 + lc]           = acc00[r];
        Xex[otype][khalf][lr + r][ng * 32 + lc + 16]      = acc01[r];
        Xex[otype][khalf][lr + r + 16][ng * 32 + lc]      = acc10[r];
        Xex[otype][khalf][lr + r + 16][ng * 32 + lc + 16] = acc11[r];
      }
    }
    __syncthreads();

    // ---- epilogue: combine K-halves, state update, publish packets ----
    float s;
    {
      const float4 p0 = *(const float4*)&Xex[0][0][bl][f0i];
      const float4 p1 = *(const float4*)&Xex[0][1][bl][f0i];
      const float4 g0 = *(const float4*)&Xex[1][0][bl][f0i];
      const float4 g1 = *(const float4*)&Xex[1][1][bl][f0i];

      const float pr[4] = {p0.x + p1.x + uxv.x, p0.y + p1.y + uxv.y,
                           p0.z + p1.z + uxv.z, p0.w + p1.w + uxv.w};
      const float gv[4] = {g0.x + g1.x, g0.y + g1.y, g0.z + g1.z, g0.w + g1.w};
      const float yov[4] = {yst.x, yst.y, yst.z, yst.w};
      float yn[4];
#pragma unroll
      for (int j = 0; j < 4; ++j) {
        // tanh(pre) = 1 - 2/(e^{2 pre}+1); sigmoid(gv) = 1/(1+e^{-gv})
        const float e2   = __expf(2.0f * pr[j]);
        const float th   = 1.0f - 2.0f * __builtin_amdgcn_rcpf(e2 + 1.0f);
        const float eg   = __expf(-gv[j]);
        const float gate = __builtin_amdgcn_rcpf(1.0f + eg);
        yn[j] = yov[j] + 0.1f * th * gate;
      }
      yst.x = yn[0]; yst.y = yn[1]; yst.z = yn[2]; yst.w = yn[3];

      // two self-validating 8B packets: [seq = t+1 | 2 x bf16]
      const ull seqw = ((ull)(unsigned)(t + 1)) << 32;
      ull* dst = pkt + (size_t)((t + 1) & 1) * 65536 + prod_base;
      __hip_atomic_store(dst,     seqw | pack2bf(yn[0], yn[1]),
                         __ATOMIC_RELAXED, __HIP_MEMORY_SCOPE_AGENT);
      __hip_atomic_store(dst + 1, seqw | pack2bf(yn[2], yn[3]),
                         __ATOMIC_RELAXED, __HIP_MEMORY_SCOPE_AGENT);

      s = yn[0] * wrov.x + yn[1] * wrov.y + yn[2] * wrov.z + yn[3] * wrov.w;
    }

    // readout partial (fire-and-forget): reduce over the 16 feature-lanes
    s += __shfl_xor(s, 1, 64);
    s += __shfl_xor(s, 2, 64);
    s += __shfl_xor(s, 4, 64);
    s += __shfl_xor(s, 8, 64);
    if ((tid & 15) == 0)
      plog[((size_t)t * 8 + slice) * B_DIM + b_glob] = s;
  }
}

// =====================================================================
// K3: out[b][t] = bro + sum_{s<8} plog[t][s][b]
// =====================================================================
__global__ __launch_bounds__(256) void k3_out(const float* __restrict__ plog,
                                              const float* __restrict__ bro,
                                              float* __restrict__ out) {
  const int t = blockIdx.x;
  const int b = threadIdx.x;
  float s = bro[0];
#pragma unroll
  for (int col = 0; col < 8; ++col)
    s += plog[((size_t)t * 8 + col) * B_DIM + b];
  out[(size_t)b * T_DIM + t] = s;
}

// =====================================================================
extern "C" void kernel_launch(void* const* d_in, const int* in_sizes, int n_in,
                              void* d_out, int out_size, void* d_ws, size_t ws_size,
                              hipStream_t stream) {
  const float* x   = (const float*)d_in[0];
  const float* y0  = (const float*)d_in[1];
  const float* W   = (const float*)d_in[2];
  const float* U   = (const float*)d_in[3];
  const float* b   = (const float*)d_in[4];
  const float* A   = (const float*)d_in[5];
  const float* Wro = (const float*)d_in[6];
  const float* bro = (const float*)d_in[7];
  float* out = (float*)d_out;

  float* ws = (float*)d_ws;
  float* Ux = ws;                                               // 33,554,432 f32
  ull* pkt = (ull*)(ws + (size_t)T_DIM * B_DIM * H_DIM);        // 2*65536 u64 (1 MB)
  float* plog = (float*)(pkt + 2 * 65536);                      // 524,288 f32

  (void)in_sizes; (void)n_in; (void)out_size; (void)ws_size;

  // MANDATORY: clear stale seq words from previous graph replays.
  hipMemsetAsync(pkt, 0, 2 * 65536 * sizeof(ull), stream);

  dim3 g1(512, 4);
  k1_ux<<<g1, 256, 0, stream>>>(x, U, b, Ux);
  k2_scan<<<64, 512, 0, stream>>>(W, A, y0, Ux, Wro, pkt, plog);
  k3_out<<<256, 256, 0, stream>>>(plog, bro, out);
}

// Round 14
// 1129.754 us; speedup vs baseline: 1.6325x; 1.6325x over previous
//
#include <hip/hip_runtime.h>
#include <cstdint>
#include <cstring>

#define H_DIM 512
#define B_DIM 256
#define T_DIM 256

typedef __bf16 bf16x8 __attribute__((ext_vector_type(8)));
typedef __bf16 bf16x4 __attribute__((ext_vector_type(4)));
typedef float  f32x4  __attribute__((ext_vector_type(4)));
typedef unsigned long long ull;

__device__ __forceinline__ void cvt_split(float4 a, float4 b, bf16x8& h, bf16x8& lo) {
  const float v[8] = {a.x, a.y, a.z, a.w, b.x, b.y, b.z, b.w};
#pragma unroll
  for (int j = 0; j < 8; ++j) {
    h[j]  = (__bf16)v[j];
    lo[j] = (__bf16)(v[j] - (float)h[j]);
  }
}

__device__ __forceinline__ unsigned pack2bf(float a, float b) {
  const __bf16 ba = (__bf16)a, bb = (__bf16)b;
  unsigned short sa, sb;
  __builtin_memcpy(&sa, &ba, 2);
  __builtin_memcpy(&sb, &bb, 2);
  return (unsigned)sa | ((unsigned)sb << 16);
}

// =====================================================================
// K1: Ux[(t*256+b)*512 + i] = sum_k x[b][t][k]*U[i][k] + bias[i]
// bf16 split-MFMA (xh@Uh + xh@Ul + xl@Uh ~ f32 accurate), f32 output.
// (R7-proven)
// =====================================================================
__global__ __launch_bounds__(256, 2) void k1_ux(const float* __restrict__ x,
                                                const float* __restrict__ U,
                                                const float* __restrict__ bias,
                                                float* __restrict__ Ux) {
  __shared__ __align__(16) __bf16 XH[128][40];
  __shared__ __align__(16) __bf16 XL[128][40];
  __shared__ __align__(16) __bf16 UH[128][40];
  __shared__ __align__(16) __bf16 UL[128][40];

  const int tid = threadIdx.x;
  const int l   = tid & 63;
  const int w   = tid >> 6;
  const int wm  = w >> 1;
  const int wn  = w & 1;
  const int r0  = blockIdx.x * 128;
  const int i0  = blockIdx.y * 128;
  const int t   = r0 >> 8;
  const int b0  = r0 & 255;

  const int srow  = tid >> 1;
  const int shalf = tid & 1;

  f32x4 acc[4][4];
#pragma unroll
  for (int mi = 0; mi < 4; ++mi)
#pragma unroll
    for (int ni = 0; ni < 4; ++ni) acc[mi][ni] = (f32x4){0.f, 0.f, 0.f, 0.f};

  const int lrow = l & 15;
  const int lgrn = (l >> 4) * 8;

  for (int k0 = 0; k0 < H_DIM; k0 += 32) {
    __syncthreads();
    {
      const float* xsrc = x + ((size_t)(b0 + srow) * T_DIM + t) * H_DIM + k0 + shalf * 16;
      const float* usrc = U + (size_t)(i0 + srow) * H_DIM + k0 + shalf * 16;
      bf16x8 h0, l0, h1, l1;
      cvt_split(*(const float4*)xsrc, *(const float4*)(xsrc + 4), h0, l0);
      cvt_split(*(const float4*)(xsrc + 8), *(const float4*)(xsrc + 12), h1, l1);
      *(bf16x8*)&XH[srow][shalf * 16]     = h0;
      *(bf16x8*)&XH[srow][shalf * 16 + 8] = h1;
      *(bf16x8*)&XL[srow][shalf * 16]     = l0;
      *(bf16x8*)&XL[srow][shalf * 16 + 8] = l1;
      cvt_split(*(const float4*)usrc, *(const float4*)(usrc + 4), h0, l0);
      cvt_split(*(const float4*)(usrc + 8), *(const float4*)(usrc + 12), h1, l1);
      *(bf16x8*)&UH[srow][shalf * 16]     = h0;
      *(bf16x8*)&UH[srow][shalf * 16 + 8] = h1;
      *(bf16x8*)&UL[srow][shalf * 16]     = l0;
      *(bf16x8*)&UL[srow][shalf * 16 + 8] = l1;
    }
    __syncthreads();

    bf16x8 ah[4], al[4], bh[4], blo[4];
#pragma unroll
    for (int mi = 0; mi < 4; ++mi) {
      ah[mi] = *(const bf16x8*)&XH[wm * 64 + mi * 16 + lrow][lgrn];
      al[mi] = *(const bf16x8*)&XL[wm * 64 + mi * 16 + lrow][lgrn];
    }
#pragma unroll
    for (int ni = 0; ni < 4; ++ni) {
      bh[ni]  = *(const bf16x8*)&UH[wn * 64 + ni * 16 + lrow][lgrn];
      blo[ni] = *(const bf16x8*)&UL[wn * 64 + ni * 16 + lrow][lgrn];
    }
#pragma unroll
    for (int mi = 0; mi < 4; ++mi)
#pragma unroll
      for (int ni = 0; ni < 4; ++ni) {
        acc[mi][ni] = __builtin_amdgcn_mfma_f32_16x16x32_bf16(ah[mi], bh[ni],  acc[mi][ni], 0, 0, 0);
        acc[mi][ni] = __builtin_amdgcn_mfma_f32_16x16x32_bf16(ah[mi], blo[ni], acc[mi][ni], 0, 0, 0);
        acc[mi][ni] = __builtin_amdgcn_mfma_f32_16x16x32_bf16(al[mi], bh[ni],  acc[mi][ni], 0, 0, 0);
      }
  }

  float bvv[4];
#pragma unroll
  for (int ni = 0; ni < 4; ++ni) bvv[ni] = bias[i0 + wn * 64 + ni * 16 + lrow];
#pragma unroll
  for (int mi = 0; mi < 4; ++mi)
#pragma unroll
    for (int ni = 0; ni < 4; ++ni) {
      const int col = i0 + wn * 64 + ni * 16 + lrow;
      const int row = r0 + wm * 64 + mi * 16 + (l >> 4) * 4;
#pragma unroll
      for (int r = 0; r < 4; ++r)
        Ux[(size_t)(row + r) * H_DIM + col] = acc[mi][ni][r] + bvv[ni];
    }
}

// =====================================================================
// K2: scan (R12 structure; batch poll + cheap representative spin).
//   64 blocks x 512 threads. bid = slice*8 + g.
//   Exchange: pkt[buf][g][row<32][fp<256] : u64 = [seq:32 | 2 x bf16].
//   Producer: 2 x 8B relaxed-atomic stores (fp = slice*32 + (tid&15)*2).
//   Consumer: UNCONDITIONAL 16-load batch sweep (parallel, 1 RT — R13's
//   conditional loads serialized into 16 RTs, -85%); if incomplete, spin
//   on ONE representative packet per lane (jrep = (scol&7)*2 covers all
//   8 producer slices per wave) — 16x less poll traffic, then re-batch.
//   WAR/replay safety unchanged from R12 (seq validation + pkt memset).
// =====================================================================
__device__ __forceinline__ unsigned swz(unsigned row, unsigned b) {
  return row * 1024u + (b ^ ((row & 7u) << 4));
}

__global__ __launch_bounds__(512, 1) void k2_scan(const float* __restrict__ W,
                                                  const float* __restrict__ Amat,
                                                  const float* __restrict__ y0,
                                                  const float* __restrict__ Ux,
                                                  const float* __restrict__ Wro,
                                                  ull* __restrict__ pkt,          // 2 x 65536 u64
                                                  float* __restrict__ plog) {     // [T][8][B]
  __shared__ __align__(16) char Ylds[32 * 1024];   // 32 rows x 512 bf16, swizzled
  __shared__ float Xex[2][2][32][68];              // [otype][khalf][b][f] padded
  const int tid   = threadIdx.x;
  const int g     = blockIdx.x & 7;
  const int slice = blockIdx.x >> 3;
  const int fbase = slice * 64;

  const int l     = tid & 63;
  const int w     = tid >> 6;        // 0..7
  const int otype = w >> 2;          // 0 = pre (W), 1 = gate (A)
  const int ng    = (w >> 1) & 1;    // feature 32-group within 64
  const int khalf = w & 1;           // K 256-split

  const int bl     = tid >> 4;       // batch 0..31
  const int f0i    = (tid & 15) * 4; // feature 0..60 (within 64-slice)
  const int b_glob = g * 32 + bl;

  // ---- own y0 state -> registers ----
  float4 yst = *(const float4*)(y0 + (size_t)b_glob * H_DIM + fbase + f0i);
  const float4 wrov = *(const float4*)(Wro + fbase + f0i);

  // ---- W/A fragments -> VGPRs (once) ----
  const int n0    = l & 15;
  const int kfrag = khalf * 256 + ((l >> 4) * 8);
  const float* Bsrc = otype ? Amat : W;
  bf16x8 bfr[2][8];
#pragma unroll
  for (int ks = 0; ks < 8; ++ks) {
#pragma unroll
    for (int h2 = 0; h2 < 2; ++h2) {
      const float* src = Bsrc + (size_t)(fbase + ng * 32 + n0 + h2 * 16) * H_DIM + kfrag + ks * 32;
      const float4 s0 = *(const float4*)src;
      const float4 s1 = *(const float4*)(src + 4);
      bf16x8 v;
      v[0] = (__bf16)s0.x; v[1] = (__bf16)s0.y; v[2] = (__bf16)s0.z; v[3] = (__bf16)s0.w;
      v[4] = (__bf16)s1.x; v[5] = (__bf16)s1.y; v[6] = (__bf16)s1.z; v[7] = (__bf16)s1.w;
      bfr[h2][ks] = v;
    }
  }

  const unsigned ra0  = (unsigned)(l & 15);
  const unsigned ra1  = ra0 + 16u;
  const unsigned coff = (unsigned)((l >> 4) * 16 + khalf * 512);

  // staging constants: this thread stages row = tid>>4, fp = (tid&15)+16j
  const unsigned srow = (unsigned)(tid >> 4);
  const unsigned scol = (unsigned)(tid & 15);
  const int jrep = (int)(scol & 7) * 2;   // representative: covers slices 0..7 per wave
  // producer constants: global fp = (fbase + f0i)/2 = slice*32 + (tid&15)*2
  const size_t prod_base = (size_t)g * 8192 + (size_t)bl * 256
                         + (size_t)slice * 32 + (size_t)(tid & 15) * 2;

  for (int t = 0; t < T_DIM; ++t) {
    // input-path term: issue before the packet wait (latency hides under it)
    const float4 uxv = *(const float4*)(Ux + ((size_t)t * B_DIM + b_glob) * H_DIM + fbase + f0i);

    // ---- stage y_t -> Ylds ----
    if (t == 0) {
#pragma unroll
      for (int j = 0; j < 16; ++j) {
        const unsigned fp = scol + 16u * j;
        const float2 v = *(const float2*)(y0 + (size_t)(g * 32 + srow) * H_DIM + fp * 2);
        *(unsigned*)(Ylds + srow * 1024u + ((fp * 4u) ^ ((srow & 7u) << 4))) = pack2bf(v.x, v.y);
      }
    } else {
      // fused poll+load: unconditional batch sweep (1 RT), cheap rep-spin wait
      const ull* src = pkt + (size_t)(t & 1) * 65536 + (size_t)g * 8192
                     + (size_t)srow * 256 + scol;
      ull pk[16];
      for (;;) {
        bool ok = true;
#pragma unroll
        for (int j = 0; j < 16; ++j) {
          pk[j] = __hip_atomic_load(src + (size_t)j * 16,
                                    __ATOMIC_RELAXED, __HIP_MEMORY_SCOPE_AGENT);
          ok &= ((unsigned)(pk[j] >> 32) == (unsigned)t);
        }
        if (__all(ok)) break;
        // cheap wait: one 8B representative per lane until valid, then re-batch
        for (;;) {
          __builtin_amdgcn_s_sleep(1);
          const ull v = __hip_atomic_load(src + (size_t)jrep * 16,
                                          __ATOMIC_RELAXED, __HIP_MEMORY_SCOPE_AGENT);
          if (__all((unsigned)(v >> 32) == (unsigned)t)) break;
        }
      }
#pragma unroll
      for (int j = 0; j < 16; ++j) {
        const unsigned fp = scol + 16u * j;
        *(unsigned*)(Ylds + srow * 1024u + ((fp * 4u) ^ ((srow & 7u) << 4))) = (unsigned)pk[j];
      }
    }
    __syncthreads();

    // ---- MFMA: 2M x 2N x 8K per wave ----
    f32x4 acc00 = {0.f, 0.f, 0.f, 0.f};
    f32x4 acc01 = {0.f, 0.f, 0.f, 0.f};
    f32x4 acc10 = {0.f, 0.f, 0.f, 0.f};
    f32x4 acc11 = {0.f, 0.f, 0.f, 0.f};
#pragma unroll
    for (int ks = 0; ks < 8; ++ks) {
      const unsigned kb = coff + (unsigned)ks * 64u;
      const bf16x8 a0 = *(const bf16x8*)(Ylds + swz(ra0, kb));
      const bf16x8 a1 = *(const bf16x8*)(Ylds + swz(ra1, kb));
      acc00 = __builtin_amdgcn_mfma_f32_16x16x32_bf16(a0, bfr[0][ks], acc00, 0, 0, 0);
      acc01 = __builtin_amdgcn_mfma_f32_16x16x32_bf16(a0, bfr[1][ks], acc01, 0, 0, 0);
      acc10 = __builtin_amdgcn_mfma_f32_16x16x32_bf16(a1, bfr[0][ks], acc10, 0, 0, 0);
      acc11 = __builtin_amdgcn_mfma_f32_16x16x32_bf16(a1, bfr[1][ks], acc11, 0, 0, 0);
    }

    // ---- partial-tile exchange ----
    {
      const int lr = (l >> 4) * 4;
      const int lc = l & 15;
#pragma unroll
      for (int r = 0; r < 4; ++r) {
        Xex[otype][khalf][lr + r][ng * 32 + lc]           = acc00[r];
        Xex[otype][khalf][lr + r][ng * 32 + lc + 16]      = acc01[r];
        Xex[otype][khalf][lr + r + 16][ng * 32 + lc]      = acc10[r];
        Xex[otype][khalf][lr + r + 16][ng * 32 + lc + 16] = acc11[r];
      }
    }
    __syncthreads();

    // ---- epilogue: combine K-halves, state update, publish packets ----
    float s;
    {
      const float4 p0 = *(const float4*)&Xex[0][0][bl][f0i];
      const float4 p1 = *(const float4*)&Xex[0][1][bl][f0i];
      const float4 g0 = *(const float4*)&Xex[1][0][bl][f0i];
      const float4 g1 = *(const float4*)&Xex[1][1][bl][f0i];

      const float pr[4] = {p0.x + p1.x + uxv.x, p0.y + p1.y + uxv.y,
                           p0.z + p1.z + uxv.z, p0.w + p1.w + uxv.w};
      const float gv[4] = {g0.x + g1.x, g0.y + g1.y, g0.z + g1.z, g0.w + g1.w};
      const float yov[4] = {yst.x, yst.y, yst.z, yst.w};
      float yn[4];
#pragma unroll
      for (int j = 0; j < 4; ++j) {
        // tanh(pre) = 1 - 2/(e^{2 pre}+1); sigmoid(gv) = 1/(1+e^{-gv})
        const float e2   = __expf(2.0f * pr[j]);
        const float th   = 1.0f - 2.0f * __builtin_amdgcn_rcpf(e2 + 1.0f);
        const float eg   = __expf(-gv[j]);
        const float gate = __builtin_amdgcn_rcpf(1.0f + eg);
        yn[j] = yov[j] + 0.1f * th * gate;
      }
      yst.x = yn[0]; yst.y = yn[1]; yst.z = yn[2]; yst.w = yn[3];

      // two self-validating 8B packets: [seq = t+1 | 2 x bf16]
      const ull seqw = ((ull)(unsigned)(t + 1)) << 32;
      ull* dst = pkt + (size_t)((t + 1) & 1) * 65536 + prod_base;
      __hip_atomic_store(dst,     seqw | pack2bf(yn[0], yn[1]),
                         __ATOMIC_RELAXED, __HIP_MEMORY_SCOPE_AGENT);
      __hip_atomic_store(dst + 1, seqw | pack2bf(yn[2], yn[3]),
                         __ATOMIC_RELAXED, __HIP_MEMORY_SCOPE_AGENT);

      s = yn[0] * wrov.x + yn[1] * wrov.y + yn[2] * wrov.z + yn[3] * wrov.w;
    }

    // readout partial (fire-and-forget): reduce over the 16 feature-lanes
    s += __shfl_xor(s, 1, 64);
    s += __shfl_xor(s, 2, 64);
    s += __shfl_xor(s, 4, 64);
    s += __shfl_xor(s, 8, 64);
    if ((tid & 15) == 0)
      plog[((size_t)t * 8 + slice) * B_DIM + b_glob] = s;
  }
}

// =====================================================================
// K3: out[b][t] = bro + sum_{s<8} plog[t][s][b]
// =====================================================================
__global__ __launch_bounds__(256) void k3_out(const float* __restrict__ plog,
                                              const float* __restrict__ bro,
                                              float* __restrict__ out) {
  const int t = blockIdx.x;
  const int b = threadIdx.x;
  float s = bro[0];
#pragma unroll
  for (int col = 0; col < 8; ++col)
    s += plog[((size_t)t * 8 + col) * B_DIM + b];
  out[(size_t)b * T_DIM + t] = s;
}

// =====================================================================
extern "C" void kernel_launch(void* const* d_in, const int* in_sizes, int n_in,
                              void* d_out, int out_size, void* d_ws, size_t ws_size,
                              hipStream_t stream) {
  const float* x   = (const float*)d_in[0];
  const float* y0  = (const float*)d_in[1];
  const float* W   = (const float*)d_in[2];
  const float* U   = (const float*)d_in[3];
  const float* b   = (const float*)d_in[4];
  const float* A   = (const float*)d_in[5];
  const float* Wro = (const float*)d_in[6];
  const float* bro = (const float*)d_in[7];
  float* out = (float*)d_out;

  float* ws = (float*)d_ws;
  float* Ux = ws;                                               // 33,554,432 f32
  ull* pkt = (ull*)(ws + (size_t)T_DIM * B_DIM * H_DIM);        // 2*65536 u64 (1 MB)
  float* plog = (float*)(pkt + 2 * 65536);                      // 524,288 f32

  (void)in_sizes; (void)n_in; (void)out_size; (void)ws_size;

  // MANDATORY: clear stale seq words from previous graph replays.
  hipMemsetAsync(pkt, 0, 2 * 65536 * sizeof(ull), stream);

  dim3 g1(512, 4);
  k1_ux<<<g1, 256, 0, stream>>>(x, U, b, Ux);
  k2_scan<<<64, 512, 0, stream>>>(W, A, y0, Ux, Wro, pkt, plog);
  k3_out<<<256, 256, 0, stream>>>(plog, bro, out);
}

// Round 16
// 1039.229 us; speedup vs baseline: 1.7747x; 1.0871x over previous
//
#include <hip/hip_runtime.h>
#include <cstdint>
#include <cstring>

#define H_DIM 512
#define B_DIM 256
#define T_DIM 256

typedef __bf16 bf16x8 __attribute__((ext_vector_type(8)));
typedef __bf16 bf16x4 __attribute__((ext_vector_type(4)));
typedef float  f32x4  __attribute__((ext_vector_type(4)));
typedef unsigned long long ull;

__device__ __forceinline__ void cvt_split(float4 a, float4 b, bf16x8& h, bf16x8& lo) {
  const float v[8] = {a.x, a.y, a.z, a.w, b.x, b.y, b.z, b.w};
#pragma unroll
  for (int j = 0; j < 8; ++j) {
    h[j]  = (__bf16)v[j];
    lo[j] = (__bf16)(v[j] - (float)h[j]);
  }
}

__device__ __forceinline__ unsigned pack2bf(float a, float b) {
  const __bf16 ba = (__bf16)a, bb = (__bf16)b;
  unsigned short sa, sb;
  __builtin_memcpy(&sa, &ba, 2);
  __builtin_memcpy(&sb, &bb, 2);
  return (unsigned)sa | ((unsigned)sb << 16);
}

// =====================================================================
// K1: Ux[(t*256+b)*512 + i] = sum_k x[b][t][k]*U[i][k] + bias[i]
// bf16 split-MFMA (xh@Uh + xh@Ul + xl@Uh ~ f32 accurate), f32 output.
// (R7-proven)
// =====================================================================
__global__ __launch_bounds__(256, 2) void k1_ux(const float* __restrict__ x,
                                                const float* __restrict__ U,
                                                const float* __restrict__ bias,
                                                float* __restrict__ Ux) {
  __shared__ __align__(16) __bf16 XH[128][40];
  __shared__ __align__(16) __bf16 XL[128][40];
  __shared__ __align__(16) __bf16 UH[128][40];
  __shared__ __align__(16) __bf16 UL[128][40];

  const int tid = threadIdx.x;
  const int l   = tid & 63;
  const int w   = tid >> 6;
  const int wm  = w >> 1;
  const int wn  = w & 1;
  const int r0  = blockIdx.x * 128;
  const int i0  = blockIdx.y * 128;
  const int t   = r0 >> 8;
  const int b0  = r0 & 255;

  const int srow  = tid >> 1;
  const int shalf = tid & 1;

  f32x4 acc[4][4];
#pragma unroll
  for (int mi = 0; mi < 4; ++mi)
#pragma unroll
    for (int ni = 0; ni < 4; ++ni) acc[mi][ni] = (f32x4){0.f, 0.f, 0.f, 0.f};

  const int lrow = l & 15;
  const int lgrn = (l >> 4) * 8;

  for (int k0 = 0; k0 < H_DIM; k0 += 32) {
    __syncthreads();
    {
      const float* xsrc = x + ((size_t)(b0 + srow) * T_DIM + t) * H_DIM + k0 + shalf * 16;
      const float* usrc = U + (size_t)(i0 + srow) * H_DIM + k0 + shalf * 16;
      bf16x8 h0, l0, h1, l1;
      cvt_split(*(const float4*)xsrc, *(const float4*)(xsrc + 4), h0, l0);
      cvt_split(*(const float4*)(xsrc + 8), *(const float4*)(xsrc + 12), h1, l1);
      *(bf16x8*)&XH[srow][shalf * 16]     = h0;
      *(bf16x8*)&XH[srow][shalf * 16 + 8] = h1;
      *(bf16x8*)&XL[srow][shalf * 16]     = l0;
      *(bf16x8*)&XL[srow][shalf * 16 + 8] = l1;
      cvt_split(*(const float4*)usrc, *(const float4*)(usrc + 4), h0, l0);
      cvt_split(*(const float4*)(usrc + 8), *(const float4*)(usrc + 12), h1, l1);
      *(bf16x8*)&UH[srow][shalf * 16]     = h0;
      *(bf16x8*)&UH[srow][shalf * 16 + 8] = h1;
      *(bf16x8*)&UL[srow][shalf * 16]     = l0;
      *(bf16x8*)&UL[srow][shalf * 16 + 8] = l1;
    }
    __syncthreads();

    bf16x8 ah[4], al[4], bh[4], blo[4];
#pragma unroll
    for (int mi = 0; mi < 4; ++mi) {
      ah[mi] = *(const bf16x8*)&XH[wm * 64 + mi * 16 + lrow][lgrn];
      al[mi] = *(const bf16x8*)&XL[wm * 64 + mi * 16 + lrow][lgrn];
    }
#pragma unroll
    for (int ni = 0; ni < 4; ++ni) {
      bh[ni]  = *(const bf16x8*)&UH[wn * 64 + ni * 16 + lrow][lgrn];
      blo[ni] = *(const bf16x8*)&UL[wn * 64 + ni * 16 + lrow][lgrn];
    }
#pragma unroll
    for (int mi = 0; mi < 4; ++mi)
#pragma unroll
      for (int ni = 0; ni < 4; ++ni) {
        acc[mi][ni] = __builtin_amdgcn_mfma_f32_16x16x32_bf16(ah[mi], bh[ni],  acc[mi][ni], 0, 0, 0);
        acc[mi][ni] = __builtin_amdgcn_mfma_f32_16x16x32_bf16(ah[mi], blo[ni], acc[mi][ni], 0, 0, 0);
        acc[mi][ni] = __builtin_amdgcn_mfma_f32_16x16x32_bf16(al[mi], bh[ni],  acc[mi][ni], 0, 0, 0);
      }
  }

  float bvv[4];
#pragma unroll
  for (int ni = 0; ni < 4; ++ni) bvv[ni] = bias[i0 + wn * 64 + ni * 16 + lrow];
#pragma unroll
  for (int mi = 0; mi < 4; ++mi)
#pragma unroll
    for (int ni = 0; ni < 4; ++ni) {
      const int col = i0 + wn * 64 + ni * 16 + lrow;
      const int row = r0 + wm * 64 + mi * 16 + (l >> 4) * 4;
#pragma unroll
      for (int r = 0; r < 4; ++r)
        Ux[(size_t)(row + r) * H_DIM + col] = acc[mi][ni][r] + bvv[ni];
    }
}

// =====================================================================
// K2: scan (R12 — proven best; fused data/seq packet sync).
//   64 blocks x 512 threads. bid = slice*8 + g.
//   Exchange: pkt[buf][g][row<32][fp<256] : u64 = [seq:32 | 2 x bf16].
//   Producer: 2 x 8B relaxed-atomic stores (fp = slice*32 + (tid&15)*2);
//   no drain, no flag. Consumer: unconditional parallel 16-load batch
//   sweep, validate hi32==t, retry -> the poll IS the data load.
//   Then swizzled LDS, barrier, MFMA 2Mx2Nx8K/wave, Xex exchange,
//   epilogue (expf). WAR-safe: overwriting buf[t&1] (seq t+2) requires
//   validating ALL seq=t+1 packets, which exist only after every block
//   passed its step-t staging barrier. Replay-safe: pkt memset per launch.
// =====================================================================
__device__ __forceinline__ unsigned swz(unsigned row, unsigned b) {
  return row * 1024u + (b ^ ((row & 7u) << 4));
}

__global__ __launch_bounds__(512, 1) void k2_scan(const float* __restrict__ W,
                                                  const float* __restrict__ Amat,
                                                  const float* __restrict__ y0,
                                                  const float* __restrict__ Ux,
                                                  const float* __restrict__ Wro,
                                                  ull* __restrict__ pkt,          // 2 x 65536 u64
                                                  float* __restrict__ plog) {     // [T][8][B]
  __shared__ __align__(16) char Ylds[32 * 1024];   // 32 rows x 512 bf16, swizzled
  __shared__ float Xex[2][2][32][68];              // [otype][khalf][b][f] padded
  const int tid   = threadIdx.x;
  const int g     = blockIdx.x & 7;
  const int slice = blockIdx.x >> 3;
  const int fbase = slice * 64;

  const int l     = tid & 63;
  const int w     = tid >> 6;        // 0..7
  const int otype = w >> 2;          // 0 = pre (W), 1 = gate (A)
  const int ng    = (w >> 1) & 1;    // feature 32-group within 64
  const int khalf = w & 1;           // K 256-split

  const int bl     = tid >> 4;       // batch 0..31
  const int f0i    = (tid & 15) * 4; // feature 0..60 (within 64-slice)
  const int b_glob = g * 32 + bl;

  // ---- own y0 state -> registers ----
  float4 yst = *(const float4*)(y0 + (size_t)b_glob * H_DIM + fbase + f0i);
  const float4 wrov = *(const float4*)(Wro + fbase + f0i);

  // ---- W/A fragments -> VGPRs (once) ----
  const int n0    = l & 15;
  const int kfrag = khalf * 256 + ((l >> 4) * 8);
  const float* Bsrc = otype ? Amat : W;
  bf16x8 bfr[2][8];
#pragma unroll
  for (int ks = 0; ks < 8; ++ks) {
#pragma unroll
    for (int h2 = 0; h2 < 2; ++h2) {
      const float* src = Bsrc + (size_t)(fbase + ng * 32 + n0 + h2 * 16) * H_DIM + kfrag + ks * 32;
      const float4 s0 = *(const float4*)src;
      const float4 s1 = *(const float4*)(src + 4);
      bf16x8 v;
      v[0] = (__bf16)s0.x; v[1] = (__bf16)s0.y; v[2] = (__bf16)s0.z; v[3] = (__bf16)s0.w;
      v[4] = (__bf16)s1.x; v[5] = (__bf16)s1.y; v[6] = (__bf16)s1.z; v[7] = (__bf16)s1.w;
      bfr[h2][ks] = v;
    }
  }

  const unsigned ra0  = (unsigned)(l & 15);
  const unsigned ra1  = ra0 + 16u;
  const unsigned coff = (unsigned)((l >> 4) * 16 + khalf * 512);

  // staging constants: this thread stages row = tid>>4, fp = (tid&15)+16j
  const unsigned srow = (unsigned)(tid >> 4);
  const unsigned scol = (unsigned)(tid & 15);
  // producer constants: global fp = (fbase + f0i)/2 = slice*32 + (tid&15)*2
  const size_t prod_base = (size_t)g * 8192 + (size_t)bl * 256
                         + (size_t)slice * 32 + (size_t)(tid & 15) * 2;

  for (int t = 0; t < T_DIM; ++t) {
    // input-path term: issue before the packet wait (latency hides under it)
    const float4 uxv = *(const float4*)(Ux + ((size_t)t * B_DIM + b_glob) * H_DIM + fbase + f0i);

    // ---- stage y_t -> Ylds ----
    if (t == 0) {
#pragma unroll
      for (int j = 0; j < 16; ++j) {
        const unsigned fp = scol + 16u * j;
        const float2 v = *(const float2*)(y0 + (size_t)(g * 32 + srow) * H_DIM + fp * 2);
        *(unsigned*)(Ylds + srow * 1024u + ((fp * 4u) ^ ((srow & 7u) << 4))) = pack2bf(v.x, v.y);
      }
    } else {
      // fused poll+load: packet hi32 must equal t
      const ull* src = pkt + (size_t)(t & 1) * 65536 + (size_t)g * 8192
                     + (size_t)srow * 256 + scol;
      ull pk[16];
      for (;;) {
        bool ok = true;
#pragma unroll
        for (int j = 0; j < 16; ++j) {
          pk[j] = __hip_atomic_load(src + (size_t)j * 16,
                                    __ATOMIC_RELAXED, __HIP_MEMORY_SCOPE_AGENT);
          ok &= ((unsigned)(pk[j] >> 32) == (unsigned)t);
        }
        if (__all(ok)) break;
        __builtin_amdgcn_s_sleep(1);
      }
#pragma unroll
      for (int j = 0; j < 16; ++j) {
        const unsigned fp = scol + 16u * j;
        *(unsigned*)(Ylds + srow * 1024u + ((fp * 4u) ^ ((srow & 7u) << 4))) = (unsigned)pk[j];
      }
    }
    __syncthreads();

    // ---- MFMA: 2M x 2N x 8K per wave ----
    f32x4 acc00 = {0.f, 0.f, 0.f, 0.f};
    f32x4 acc01 = {0.f, 0.f, 0.f, 0.f};
    f32x4 acc10 = {0.f, 0.f, 0.f, 0.f};
    f32x4 acc11 = {0.f, 0.f, 0.f, 0.f};
#pragma unroll
    for (int ks = 0; ks < 8; ++ks) {
      const unsigned kb = coff + (unsigned)ks * 64u;
      const bf16x8 a0 = *(const bf16x8*)(Ylds + swz(ra0, kb));
      const bf16x8 a1 = *(const bf16x8*)(Ylds + swz(ra1, kb));
      acc00 = __builtin_amdgcn_mfma_f32_16x16x32_bf16(a0, bfr[0][ks], acc00, 0, 0, 0);
      acc01 = __builtin_amdgcn_mfma_f32_16x16x32_bf16(a0, bfr[1][ks], acc01, 0, 0, 0);
      acc10 = __builtin_amdgcn_mfma_f32_16x16x32_bf16(a1, bfr[0][ks], acc10, 0, 0, 0);
      acc11 = __builtin_amdgcn_mfma_f32_16x16x32_bf16(a1, bfr[1][ks], acc11, 0, 0, 0);
    }

    // ---- partial-tile exchange ----
    {
      const int lr = (l >> 4) * 4;
      const int lc = l & 15;
#pragma unroll
      for (int r = 0; r < 4; ++r) {
        Xex[otype][khalf][lr + r][ng * 32 + lc]           = acc00[r];
        Xex[otype][khalf][lr + r][ng * 32 + lc + 16]      = acc01[r];
        Xex[otype][khalf][lr + r + 16][ng * 32 + lc]      = acc10[r];
        Xex[otype][khalf][lr + r + 16][ng * 32 + lc + 16] = acc11[r];
      }
    }
    __syncthreads();

    // ---- epilogue: combine K-halves, state update, publish packets ----
    float s;
    {
      const float4 p0 = *(const float4*)&Xex[0][0][bl][f0i];
      const float4 p1 = *(const float4*)&Xex[0][1][bl][f0i];
      const float4 g0 = *(const float4*)&Xex[1][0][bl][f0i];
      const float4 g1 = *(const float4*)&Xex[1][1][bl][f0i];

      const float pr[4] = {p0.x + p1.x + uxv.x, p0.y + p1.y + uxv.y,
                           p0.z + p1.z + uxv.z, p0.w + p1.w + uxv.w};
      const float gv[4] = {g0.x + g1.x, g0.y + g1.y, g0.z + g1.z, g0.w + g1.w};
      const float yov[4] = {yst.x, yst.y, yst.z, yst.w};
      float yn[4];
#pragma unroll
      for (int j = 0; j < 4; ++j) {
        // tanh(pre) = 1 - 2/(e^{2 pre}+1); sigmoid(gv) = 1/(1+e^{-gv})
        const float e2   = __expf(2.0f * pr[j]);
        const float th   = 1.0f - 2.0f * __builtin_amdgcn_rcpf(e2 + 1.0f);
        const float eg   = __expf(-gv[j]);
        const float gate = __builtin_amdgcn_rcpf(1.0f + eg);
        yn[j] = yov[j] + 0.1f * th * gate;
      }
      yst.x = yn[0]; yst.y = yn[1]; yst.z = yn[2]; yst.w = yn[3];

      // two self-validating 8B packets: [seq = t+1 | 2 x bf16]
      const ull seqw = ((ull)(unsigned)(t + 1)) << 32;
      ull* dst = pkt + (size_t)((t + 1) & 1) * 65536 + prod_base;
      __hip_atomic_store(dst,     seqw | pack2bf(yn[0], yn[1]),
                         __ATOMIC_RELAXED, __HIP_MEMORY_SCOPE_AGENT);
      __hip_atomic_store(dst + 1, seqw | pack2bf(yn[2], yn[3]),
                         __ATOMIC_RELAXED, __HIP_MEMORY_SCOPE_AGENT);

      s = yn[0] * wrov.x + yn[1] * wrov.y + yn[2] * wrov.z + yn[3] * wrov.w;
    }

    // readout partial (fire-and-forget): reduce over the 16 feature-lanes
    s += __shfl_xor(s, 1, 64);
    s += __shfl_xor(s, 2, 64);
    s += __shfl_xor(s, 4, 64);
    s += __shfl_xor(s, 8, 64);
    if ((tid & 15) == 0)
      plog[((size_t)t * 8 + slice) * B_DIM + b_glob] = s;
  }
}

// =====================================================================
// K3: out[b][t] = bro + sum_{s<8} plog[t][s][b]
// =====================================================================
__global__ __launch_bounds__(256) void k3_out(const float* __restrict__ plog,
                                              const float* __restrict__ bro,
                                              float* __restrict__ out) {
  const int t = blockIdx.x;
  const int b = threadIdx.x;
  float s = bro[0];
#pragma unroll
  for (int col = 0; col < 8; ++col)
    s += plog[((size_t)t * 8 + col) * B_DIM + b];
  out[(size_t)b * T_DIM + t] = s;
}

// =====================================================================
extern "C" void kernel_launch(void* const* d_in, const int* in_sizes, int n_in,
                              void* d_out, int out_size, void* d_ws, size_t ws_size,
                              hipStream_t stream) {
  const float* x   = (const float*)d_in[0];
  const float* y0  = (const float*)d_in[1];
  const float* W   = (const float*)d_in[2];
  const float* U   = (const float*)d_in[3];
  const float* b   = (const float*)d_in[4];
  const float* A   = (const float*)d_in[5];
  const float* Wro = (const float*)d_in[6];
  const float* bro = (const float*)d_in[7];
  float* out = (float*)d_out;

  float* ws = (float*)d_ws;
  float* Ux = ws;                                               // 33,554,432 f32
  ull* pkt = (ull*)(ws + (size_t)T_DIM * B_DIM * H_DIM);        // 2*65536 u64 (1 MB)
  float* plog = (float*)(pkt + 2 * 65536);                      // 524,288 f32

  (void)in_sizes; (void)n_in; (void)out_size; (void)ws_size;

  // MANDATORY: clear stale seq words from previous graph replays.
  hipMemsetAsync(pkt, 0, 2 * 65536 * sizeof(ull), stream);

  dim3 g1(512, 4);
  k1_ux<<<g1, 256, 0, stream>>>(x, U, b, Ux);
  k2_scan<<<64, 512, 0, stream>>>(W, A, y0, Ux, Wro, pkt, plog);
  k3_out<<<256, 256, 0, stream>>>(plog, bro, out);
}